// Round 2
// baseline (15496.552 us; speedup 1.0000x reference)
//
#include <hip/hip_runtime.h>
#include <hip/hip_bf16.h>

#define DIM 768
#define NH 12
#define HD 64
#define SEQ 1024
#define BATCH 8

__device__ __forceinline__ float bfraw2f(unsigned u) { return __uint_as_float(u << 16); }
__device__ __forceinline__ unsigned short f2bf(float f) {
  unsigned u = __float_as_uint(f);
  return (unsigned short)((u + 0x7fffu + ((u >> 16) & 1u)) >> 16);
}

// ---------------------------------------------------------------------------
// K1: QKV projection. X(8192x768 fp32) @ W(768x768 fp32) -> [B][H][N][HD] bf16.
// blockIdx.z selects Wq/Wk/Wv; q scaled by HD^-0.5.
// 64x64 tile, BK=16, 256 threads, 4x4 micro-tile.
// ---------------------------------------------------------------------------
__global__ __launch_bounds__(256) void gemm_qkv(
    const float* __restrict__ X,
    const float* __restrict__ Wq,
    const float* __restrict__ Wk,
    const float* __restrict__ Wv,
    unsigned short* __restrict__ Qo, unsigned short* __restrict__ Ko,
    unsigned short* __restrict__ Vo)
{
  const int z = blockIdx.z;
  const float* W = (z == 0) ? Wq : (z == 1) ? Wk : Wv;
  unsigned short* D = (z == 0) ? Qo : (z == 1) ? Ko : Vo;
  const float scale = (z == 0) ? 0.125f : 1.0f;  // HD^-0.5 = 1/8 on q

  __shared__ float As[64 * 20];   // pad 20: aligned f4 stores, 2-way reads (free)
  __shared__ float Bs[16 * 68];

  const int t = threadIdx.x;
  const int tx = t & 15, ty = t >> 4;
  const int row0 = blockIdx.y * 64;
  const int col0 = blockIdx.x * 64;

  const int ar = t >> 2, ac = (t & 3) * 4;   // A tile 64x16
  const int br = t >> 4, bc = (t & 15) * 4;  // B tile 16x64

  float acc[4][4] = {};

  for (int k0 = 0; k0 < DIM; k0 += 16) {
    __syncthreads();
    *(float4*)&As[ar * 20 + ac] = *(const float4*)(X + (size_t)(row0 + ar) * DIM + k0 + ac);
    *(float4*)&Bs[br * 68 + bc] = *(const float4*)(W + (size_t)(k0 + br) * DIM + col0 + bc);
    __syncthreads();
#pragma unroll
    for (int k = 0; k < 16; ++k) {
      float a0 = As[(ty * 4 + 0) * 20 + k];
      float a1 = As[(ty * 4 + 1) * 20 + k];
      float a2 = As[(ty * 4 + 2) * 20 + k];
      float a3 = As[(ty * 4 + 3) * 20 + k];
      float4 bv = *(const float4*)&Bs[k * 68 + tx * 4];
      acc[0][0] += a0 * bv.x; acc[0][1] += a0 * bv.y; acc[0][2] += a0 * bv.z; acc[0][3] += a0 * bv.w;
      acc[1][0] += a1 * bv.x; acc[1][1] += a1 * bv.y; acc[1][2] += a1 * bv.z; acc[1][3] += a1 * bv.w;
      acc[2][0] += a2 * bv.x; acc[2][1] += a2 * bv.y; acc[2][2] += a2 * bv.z; acc[2][3] += a2 * bv.w;
      acc[3][0] += a3 * bv.x; acc[3][1] += a3 * bv.y; acc[3][2] += a3 * bv.z; acc[3][3] += a3 * bv.w;
    }
  }

  const int col = col0 + tx * 4;        // 4 consecutive d within one head
  const int h = col >> 6, dd = col & 63;
#pragma unroll
  for (int u = 0; u < 4; ++u) {
    int row = row0 + ty * 4 + u;
    int bb = row >> 10, ii = row & 1023;
    ushort4 pk;
    pk.x = f2bf(acc[u][0] * scale);
    pk.y = f2bf(acc[u][1] * scale);
    pk.z = f2bf(acc[u][2] * scale);
    pk.w = f2bf(acc[u][3] * scale);
    *(ushort4*)&D[((size_t)((bb * NH + h) * SEQ + ii)) * HD + dd] = pk;
  }
}

// ---------------------------------------------------------------------------
// K2: fused talking-heads attention. One block per (b, 16-row i-tile).
// Phase A: sweep j, online softmax stats (m,l) per (g, row) of mixed scores.
// Phase B: sweep j again, normalize, post-mix, accumulate P2 @ V.
// Q/K/V are bf16 in ws; all math fp32. No N x N tensor materialized.
// ---------------------------------------------------------------------------
__global__ __launch_bounds__(256) void attn_fused(
    const unsigned short* __restrict__ Qg, const unsigned short* __restrict__ Kg,
    const unsigned short* __restrict__ Vg,
    const float* __restrict__ Wl, const float* __restrict__ bl,
    const float* __restrict__ Ww, const float* __restrict__ bw,
    unsigned short* __restrict__ Aout)
{
  __shared__ float qs[NH * HD * 16];    // [h][d][ti] -> conflict-free compute reads
  __shared__ float p2s[NH * 16 * 17];   // [g2][ti][tj], pad 17
  __shared__ float mlm[NH * 16];        // row max per (g, ti)
  __shared__ float mli[NH * 16];        // 1/l per (g, ti)
  __shared__ float wls[NH * NH], wws[NH * NH], bls[NH], bws[NH];

  const int t = threadIdx.x;
  const int tj = t & 15, ti = t >> 4;   // phase A/S mapping: (row ti, col tj)
  const int b = blockIdx.y;
  const int i0 = blockIdx.x * 16;

  if (t < NH * NH) { wls[t] = Wl[t]; wws[t] = Ww[t]; }
  if (t < NH)      { bls[t] = bl[t]; bws[t] = bw[t]; }

  const size_t bbase = (size_t)b * NH * SEQ * HD;

  // stage Q rows (already scaled) for all heads: [h][d][ti]
  for (int idx = t; idx < NH * 16 * HD / 4; idx += 256) {
    int d4 = idx & 15;
    int r = idx >> 4;
    int tti = r & 15, h = r >> 4;
    uint2 raw = *(const uint2*)(Qg + bbase + ((size_t)h * SEQ + i0 + tti) * HD + d4 * 4);
    int base = (h * HD + d4 * 4) * 16 + tti;
    qs[base + 0 * 16] = bfraw2f(raw.x & 0xffffu);
    qs[base + 1 * 16] = bfraw2f(raw.x >> 16);
    qs[base + 2 * 16] = bfraw2f(raw.y & 0xffffu);
    qs[base + 3 * 16] = bfraw2f(raw.y >> 16);
  }
  __syncthreads();

  // s[h] = q[b,h,i0+ti,:] . K[b,h,j,:]
  auto computeS = [&](int j, float* s) {
#pragma unroll
    for (int h = 0; h < NH; ++h) {
      const uint4* kp = (const uint4*)(Kg + bbase + ((size_t)h * SEQ + j) * HD);
      const float* qp = &qs[(h * HD) * 16 + ti];
      float a = 0.f;
#pragma unroll
      for (int c = 0; c < 8; ++c) {
        uint4 r = kp[c];
        a += bfraw2f(r.x & 0xffffu) * qp[(c * 8 + 0) * 16];
        a += bfraw2f(r.x >> 16)     * qp[(c * 8 + 1) * 16];
        a += bfraw2f(r.y & 0xffffu) * qp[(c * 8 + 2) * 16];
        a += bfraw2f(r.y >> 16)     * qp[(c * 8 + 3) * 16];
        a += bfraw2f(r.z & 0xffffu) * qp[(c * 8 + 4) * 16];
        a += bfraw2f(r.z >> 16)     * qp[(c * 8 + 5) * 16];
        a += bfraw2f(r.w & 0xffffu) * qp[(c * 8 + 6) * 16];
        a += bfraw2f(r.w >> 16)     * qp[(c * 8 + 7) * 16];
      }
      s[h] = a;
    }
  };

  // ---- Phase A: softmax stats over mixed scores ----
  float m_run[NH], l_run[NH];
#pragma unroll
  for (int g = 0; g < NH; ++g) { m_run[g] = -1e30f; l_run[g] = 0.f; }

  for (int jt = 0; jt < SEQ / 16; ++jt) {
    int j = jt * 16 + tj;
    float s[NH];
    computeS(j, s);
#pragma unroll
    for (int g = 0; g < NH; ++g) {
      float sm = bls[g];
#pragma unroll
      for (int h = 0; h < NH; ++h) sm += wls[g * NH + h] * s[h];
      float mx = sm;
      mx = fmaxf(mx, __shfl_xor(mx, 1));
      mx = fmaxf(mx, __shfl_xor(mx, 2));
      mx = fmaxf(mx, __shfl_xor(mx, 4));
      mx = fmaxf(mx, __shfl_xor(mx, 8));
      float mn = fmaxf(m_run[g], mx);
      float e = __expf(sm - mn);
      float es = e;
      es += __shfl_xor(es, 1);
      es += __shfl_xor(es, 2);
      es += __shfl_xor(es, 4);
      es += __shfl_xor(es, 8);
      l_run[g] = l_run[g] * __expf(m_run[g] - mn) + es;
      m_run[g] = mn;
    }
  }
  if (tj == 0) {
#pragma unroll
    for (int g = 0; g < NH; ++g) {
      mlm[g * 16 + ti] = m_run[g];
      mli[g * 16 + ti] = 1.0f / l_run[g];
    }
  }
  __syncthreads();

  // ---- Phase B: normalize, post-mix, PV-accumulate ----
  float acc[NH][4] = {};

  for (int jt = 0; jt < SEQ / 16; ++jt) {
    int j = jt * 16 + tj;
    float s[NH];
    computeS(j, s);
    float p[NH];
#pragma unroll
    for (int g = 0; g < NH; ++g) {
      float sm = bls[g];
#pragma unroll
      for (int h = 0; h < NH; ++h) sm += wls[g * NH + h] * s[h];
      p[g] = __expf(sm - mlm[g * 16 + ti]) * mli[g * 16 + ti];
    }
#pragma unroll
    for (int g2 = 0; g2 < NH; ++g2) {
      float v = bws[g2];
#pragma unroll
      for (int g = 0; g < NH; ++g) v += wws[g2 * NH + g] * p[g];
      p2s[(g2 * 16 + ti) * 17 + tj] = v;
    }
    __syncthreads();
    // PV: thread owns (row i2 = tj, d-slice dg = ti)
#pragma unroll
    for (int g2 = 0; g2 < NH; ++g2) {
      const unsigned short* vrow = Vg + bbase + ((size_t)g2 * SEQ + jt * 16) * HD + ti * 4;
      const float* pp = &p2s[(g2 * 16 + tj) * 17];
#pragma unroll
      for (int jj = 0; jj < 16; ++jj) {
        float pv = pp[jj];
        uint2 r = *(const uint2*)(vrow + (size_t)jj * HD);
        acc[g2][0] += pv * bfraw2f(r.x & 0xffffu);
        acc[g2][1] += pv * bfraw2f(r.x >> 16);
        acc[g2][2] += pv * bfraw2f(r.y & 0xffffu);
        acc[g2][3] += pv * bfraw2f(r.y >> 16);
      }
    }
    __syncthreads();
  }

  // write attn output rows (B,N,C) bf16; row = i0 + tj, cols g2*64 + ti*4 ..+3
#pragma unroll
  for (int g2 = 0; g2 < NH; ++g2) {
    ushort4 pk;
    pk.x = f2bf(acc[g2][0]);
    pk.y = f2bf(acc[g2][1]);
    pk.z = f2bf(acc[g2][2]);
    pk.w = f2bf(acc[g2][3]);
    *(ushort4*)&Aout[((size_t)b * SEQ + i0 + tj) * DIM + g2 * HD + ti * 4] = pk;
  }
}

// ---------------------------------------------------------------------------
// K3: output projection. A(8192x768 bf16) @ Wp(fp32) + bp -> fp32 out.
// ---------------------------------------------------------------------------
__global__ __launch_bounds__(256) void gemm_proj(
    const unsigned short* __restrict__ A,
    const float* __restrict__ Wp,
    const float* __restrict__ bp,
    float* __restrict__ Out)
{
  __shared__ float As[64 * 20];
  __shared__ float Bs[16 * 68];

  const int t = threadIdx.x;
  const int tx = t & 15, ty = t >> 4;
  const int row0 = blockIdx.y * 64;
  const int col0 = blockIdx.x * 64;

  const int ar = t >> 2, ac = (t & 3) * 4;
  const int br = t >> 4, bc = (t & 15) * 4;

  float acc[4][4] = {};

  for (int k0 = 0; k0 < DIM; k0 += 16) {
    __syncthreads();
    {
      uint2 raw = *(const uint2*)(A + (size_t)(row0 + ar) * DIM + k0 + ac);
      float4 v = make_float4(bfraw2f(raw.x & 0xffffu), bfraw2f(raw.x >> 16),
                             bfraw2f(raw.y & 0xffffu), bfraw2f(raw.y >> 16));
      *(float4*)&As[ar * 20 + ac] = v;
    }
    *(float4*)&Bs[br * 68 + bc] = *(const float4*)(Wp + (size_t)(k0 + br) * DIM + col0 + bc);
    __syncthreads();
#pragma unroll
    for (int k = 0; k < 16; ++k) {
      float a0 = As[(ty * 4 + 0) * 20 + k];
      float a1 = As[(ty * 4 + 1) * 20 + k];
      float a2 = As[(ty * 4 + 2) * 20 + k];
      float a3 = As[(ty * 4 + 3) * 20 + k];
      float4 bv = *(const float4*)&Bs[k * 68 + tx * 4];
      acc[0][0] += a0 * bv.x; acc[0][1] += a0 * bv.y; acc[0][2] += a0 * bv.z; acc[0][3] += a0 * bv.w;
      acc[1][0] += a1 * bv.x; acc[1][1] += a1 * bv.y; acc[1][2] += a1 * bv.z; acc[1][3] += a1 * bv.w;
      acc[2][0] += a2 * bv.x; acc[2][1] += a2 * bv.y; acc[2][2] += a2 * bv.z; acc[2][3] += a2 * bv.w;
      acc[3][0] += a3 * bv.x; acc[3][1] += a3 * bv.y; acc[3][2] += a3 * bv.z; acc[3][3] += a3 * bv.w;
    }
  }

  const int col = col0 + tx * 4;
  float4 bb4 = *(const float4*)(bp + col);
#pragma unroll
  for (int u = 0; u < 4; ++u) {
    int row = row0 + ty * 4 + u;
    float4 o = make_float4(acc[u][0] + bb4.x, acc[u][1] + bb4.y,
                           acc[u][2] + bb4.z, acc[u][3] + bb4.w);
    *(float4*)&Out[(size_t)row * DIM + col] = o;
  }
}

extern "C" void kernel_launch(void* const* d_in, const int* in_sizes, int n_in,
                              void* d_out, int out_size, void* d_ws, size_t ws_size,
                              hipStream_t stream) {
  const float* x  = (const float*)d_in[0];
  const float* Wq = (const float*)d_in[1];
  const float* Wk = (const float*)d_in[2];
  const float* Wv = (const float*)d_in[3];
  const float* Wl = (const float*)d_in[4];
  const float* bl = (const float*)d_in[5];
  const float* Ww = (const float*)d_in[6];
  const float* bw = (const float*)d_in[7];
  const float* Wp = (const float*)d_in[8];
  const float* bp = (const float*)d_in[9];

  unsigned short* ws = (unsigned short*)d_ws;
  const size_t QSZ = (size_t)BATCH * NH * SEQ * HD;  // 6291456 elements
  unsigned short* Q  = ws;
  unsigned short* K  = ws + QSZ;
  unsigned short* V  = ws + 2 * QSZ;
  unsigned short* AO = ws + 3 * QSZ;

  gemm_qkv<<<dim3(DIM / 64, (BATCH * SEQ) / 64, 3), 256, 0, stream>>>(x, Wq, Wk, Wv, Q, K, V);
  attn_fused<<<dim3(SEQ / 16, BATCH), 256, 0, stream>>>(Q, K, V, Wl, bl, Ww, bw, AO);
  gemm_proj<<<dim3(DIM / 64, (BATCH * SEQ) / 64), 256, 0, stream>>>(AO, Wp, bp, (float*)d_out);
}

// Round 3
// 1933.605 us; speedup vs baseline: 8.0143x; 8.0143x over previous
//
#include <hip/hip_runtime.h>
#include <hip/hip_bf16.h>

#define DIM 768
#define NH 12
#define HD 64
#define SEQ 1024
#define BATCH 8

typedef __bf16 bf16x8 __attribute__((ext_vector_type(8)));
typedef __bf16 bf16x4 __attribute__((ext_vector_type(4)));
typedef _Float16 f16x4 __attribute__((ext_vector_type(4)));
typedef float f32x4 __attribute__((ext_vector_type(4)));

__device__ __forceinline__ float bfraw2f(unsigned u) { return __uint_as_float(u << 16); }

// ---------------------------------------------------------------------------
// K1: QKV projection. X(8192x768 fp32) @ W(768x768 fp32).
// z=0: Q*scale -> bf16 [b][h][i][d]; z=1: K -> bf16 [b][h][j][d];
// z=2: V -> fp16 TRANSPOSED [b][h][d][j] (for PV MFMA B-frags).
// ---------------------------------------------------------------------------
__global__ __launch_bounds__(256) void gemm_qkv(
    const float* __restrict__ X,
    const float* __restrict__ Wq,
    const float* __restrict__ Wk,
    const float* __restrict__ Wv,
    __bf16* __restrict__ Qo, __bf16* __restrict__ Ko,
    _Float16* __restrict__ Vt)
{
  const int z = blockIdx.z;
  const float* W = (z == 0) ? Wq : (z == 1) ? Wk : Wv;
  const float scale = (z == 0) ? 0.125f : 1.0f;  // HD^-0.5 = 1/8 on q

  __shared__ float As[64 * 20];
  __shared__ float Bs[16 * 68];

  const int t = threadIdx.x;
  const int tx = t & 15, ty = t >> 4;
  const int row0 = blockIdx.y * 64;
  const int col0 = blockIdx.x * 64;

  const int ar = t >> 2, ac = (t & 3) * 4;   // A tile 64x16
  const int br = t >> 4, bc = (t & 15) * 4;  // B tile 16x64

  float acc[4][4] = {};

  for (int k0 = 0; k0 < DIM; k0 += 16) {
    __syncthreads();
    *(float4*)&As[ar * 20 + ac] = *(const float4*)(X + (size_t)(row0 + ar) * DIM + k0 + ac);
    *(float4*)&Bs[br * 68 + bc] = *(const float4*)(W + (size_t)(k0 + br) * DIM + col0 + bc);
    __syncthreads();
#pragma unroll
    for (int k = 0; k < 16; ++k) {
      float a0 = As[(ty * 4 + 0) * 20 + k];
      float a1 = As[(ty * 4 + 1) * 20 + k];
      float a2 = As[(ty * 4 + 2) * 20 + k];
      float a3 = As[(ty * 4 + 3) * 20 + k];
      float4 bv = *(const float4*)&Bs[k * 68 + tx * 4];
      acc[0][0] += a0 * bv.x; acc[0][1] += a0 * bv.y; acc[0][2] += a0 * bv.z; acc[0][3] += a0 * bv.w;
      acc[1][0] += a1 * bv.x; acc[1][1] += a1 * bv.y; acc[1][2] += a1 * bv.z; acc[1][3] += a1 * bv.w;
      acc[2][0] += a2 * bv.x; acc[2][1] += a2 * bv.y; acc[2][2] += a2 * bv.z; acc[2][3] += a2 * bv.w;
      acc[3][0] += a3 * bv.x; acc[3][1] += a3 * bv.y; acc[3][2] += a3 * bv.z; acc[3][3] += a3 * bv.w;
    }
  }

  const int col = col0 + tx * 4;        // 4 consecutive d within one head
  const int h = col >> 6, dd = col & 63;
  const int bb = row0 >> 10;

  if (z == 2) {
    // transposed fp16 store: Vt[(bb*NH+h)*HD + d][j], 4 consecutive j per store
    const int jj0 = (row0 & 1023) + ty * 4;
#pragma unroll
    for (int c = 0; c < 4; ++c) {
      f16x4 pk = { (_Float16)acc[0][c], (_Float16)acc[1][c],
                   (_Float16)acc[2][c], (_Float16)acc[3][c] };
      *(f16x4*)(Vt + ((size_t)((bb * NH + h) * HD) + dd + c) * SEQ + jj0) = pk;
    }
  } else {
    __bf16* D = (z == 0) ? Qo : Ko;
#pragma unroll
    for (int u = 0; u < 4; ++u) {
      int row = row0 + ty * 4 + u;
      int ii = row & 1023;
      bf16x4 pk = { (__bf16)(acc[u][0] * scale), (__bf16)(acc[u][1] * scale),
                    (__bf16)(acc[u][2] * scale), (__bf16)(acc[u][3] * scale) };
      *(bf16x4*)(&D[((size_t)((bb * NH + h) * SEQ + ii)) * HD + dd]) = pk;
    }
  }
}

// ---------------------------------------------------------------------------
// K2: fused talking-heads attention, MFMA version.
// Block = (b, 16 q-rows), 4 waves. Wave w owns heads {3w..3w+2} for the
// QK^T MFMAs and the same set as g2 for post-mix + PV.
// S^T tiles via mfma_f32_16x16x32_bf16 -> lane holds S[i=lane&15][j=quad*4+r]
// (A-operand layout for PV). Softmax with FIXED max=0 (mixed scores are
// O(1); exp cannot overflow fp32) -> no running-max/rescale machinery.
// Phase A: accumulate row sums l_g. Phase B: Pn = exp*linv, pre-mix via LDS
// head-exchange, post-mix in registers, PV via mfma_f32_16x16x16f16.
// ---------------------------------------------------------------------------
__global__ __launch_bounds__(256) void attn_fused(
    const __bf16* __restrict__ Qg, const __bf16* __restrict__ Kg,
    const _Float16* __restrict__ Vt,
    const float* __restrict__ Wl, const float* __restrict__ bl,
    const float* __restrict__ Ww, const float* __restrict__ bw,
    __bf16* __restrict__ Aout)
{
  __shared__ float Slds[2][NH][16][18];   // [buf][h][j][i+pad] (2-way banks: free)
  __shared__ float wls[NH * NH], wws[NH * NH], bls[NH], bws[NH];

  const int t = threadIdx.x;
  const int lane = t & 63;
  const int w = t >> 6;          // wave id, owns heads h0..h0+2
  const int h0 = w * 3;
  const int n = lane & 15;       // i-index (C-col of S^T)
  const int quad = lane >> 4;
  const int b = blockIdx.y;
  const int i0 = blockIdx.x * 16;

  if (t < NH * NH) { wls[t] = Wl[t]; wws[t] = Ww[t]; }
  if (t < NH)      { bls[t] = bl[t]; bws[t] = bw[t]; }
  // visibility of weights guaranteed by the first jt barrier below.

  const size_t bbase = (size_t)b * NH * SEQ * HD;

  // Q B-frags for own 3 heads (reused across all jt): B[k=quad*8+j][n] = Q[n][k]
  bf16x8 qf[3][2];
#pragma unroll
  for (int hh = 0; hh < 3; ++hh)
#pragma unroll
    for (int c = 0; c < 2; ++c)
      qf[hh][c] = *(const bf16x8*)(Qg + bbase + ((size_t)(h0 + hh) * SEQ + i0 + n) * HD + c * 32 + quad * 8);

  const f32x4 zacc = {0.f, 0.f, 0.f, 0.f};

  // ---------------- Phase A: row sums l_g (fixed max = 0) ----------------
  float lrun[NH];
#pragma unroll
  for (int g = 0; g < NH; ++g) lrun[g] = 0.f;

  for (int jt = 0; jt < SEQ / 16; ++jt) {
    const int buf = jt & 1;
#pragma unroll
    for (int hh = 0; hh < 3; ++hh) {
      const __bf16* kp = Kg + bbase + ((size_t)(h0 + hh) * SEQ + jt * 16 + n) * HD;
      bf16x8 kf0 = *(const bf16x8*)(kp + quad * 8);
      bf16x8 kf1 = *(const bf16x8*)(kp + 32 + quad * 8);
      f32x4 sacc = __builtin_amdgcn_mfma_f32_16x16x32_bf16(kf0, qf[hh][0], zacc, 0, 0, 0);
      sacc = __builtin_amdgcn_mfma_f32_16x16x32_bf16(kf1, qf[hh][1], sacc, 0, 0, 0);
#pragma unroll
      for (int r = 0; r < 4; ++r)
        Slds[buf][h0 + hh][quad * 4 + r][n] = sacc[r];
    }
    __syncthreads();
#pragma unroll
    for (int r = 0; r < 4; ++r) {
      float sv[NH];
#pragma unroll
      for (int h = 0; h < NH; ++h) sv[h] = Slds[buf][h][quad * 4 + r][n];
#pragma unroll
      for (int g = 0; g < NH; ++g) {
        float sm = bls[g];
#pragma unroll
        for (int h = 0; h < NH; ++h) sm += wls[g * NH + h] * sv[h];
        lrun[g] += __expf(sm);
      }
    }
  }
  // combine quads (each quad summed its own j subset), then invert
  float linv[NH];
#pragma unroll
  for (int g = 0; g < NH; ++g) {
    float l = lrun[g];
    l += __shfl_xor(l, 16);
    l += __shfl_xor(l, 32);
    linv[g] = 1.0f / l;
  }

  // ---------------- Phase B: Pn, pre-mix, post-mix, PV -------------------
  f32x4 oacc[3][4];
#pragma unroll
  for (int hh = 0; hh < 3; ++hh)
#pragma unroll
    for (int dc = 0; dc < 4; ++dc) oacc[hh][dc] = zacc;

  for (int jt = 0; jt < SEQ / 16; ++jt) {
    const int buf = jt & 1;
#pragma unroll
    for (int hh = 0; hh < 3; ++hh) {
      const __bf16* kp = Kg + bbase + ((size_t)(h0 + hh) * SEQ + jt * 16 + n) * HD;
      bf16x8 kf0 = *(const bf16x8*)(kp + quad * 8);
      bf16x8 kf1 = *(const bf16x8*)(kp + 32 + quad * 8);
      f32x4 sacc = __builtin_amdgcn_mfma_f32_16x16x32_bf16(kf0, qf[hh][0], zacc, 0, 0, 0);
      sacc = __builtin_amdgcn_mfma_f32_16x16x32_bf16(kf1, qf[hh][1], sacc, 0, 0, 0);
#pragma unroll
      for (int r = 0; r < 4; ++r)
        Slds[buf][h0 + hh][quad * 4 + r][n] = sacc[r];
    }
    __syncthreads();

    float p2v[3][4];
#pragma unroll
    for (int r = 0; r < 4; ++r) {
      float sv[NH];
#pragma unroll
      for (int h = 0; h < NH; ++h) sv[h] = Slds[buf][h][quad * 4 + r][n];
      float pn[NH];
#pragma unroll
      for (int g = 0; g < NH; ++g) {
        float sm = bls[g];
#pragma unroll
        for (int h = 0; h < NH; ++h) sm += wls[g * NH + h] * sv[h];
        pn[g] = __expf(sm) * linv[g];
      }
#pragma unroll
      for (int hh = 0; hh < 3; ++hh) {
        int g2 = h0 + hh;
        float v = bws[g2];
#pragma unroll
        for (int g = 0; g < NH; ++g) v += wws[g2 * NH + g] * pn[g];
        p2v[hh][r] = v;
      }
    }

#pragma unroll
    for (int hh = 0; hh < 3; ++hh) {
      int g2 = h0 + hh;
      f16x4 pf = { (_Float16)p2v[hh][0], (_Float16)p2v[hh][1],
                   (_Float16)p2v[hh][2], (_Float16)p2v[hh][3] };
      const _Float16* vb = Vt + ((size_t)(b * NH + g2) * HD) * SEQ + jt * 16 + quad * 4;
#pragma unroll
      for (int dc = 0; dc < 4; ++dc) {
        f16x4 vf = *(const f16x4*)(vb + (size_t)(dc * 16 + n) * SEQ);
        oacc[hh][dc] = __builtin_amdgcn_mfma_f32_16x16x16f16(pf, vf, oacc[hh][dc], 0, 0, 0);
      }
    }
  }

  // epilogue: O C-layout row i=quad*4+r, col d=dc*16+n; write bf16 AO[b][i][c]
#pragma unroll
  for (int hh = 0; hh < 3; ++hh)
#pragma unroll
    for (int dc = 0; dc < 4; ++dc)
#pragma unroll
      for (int r = 0; r < 4; ++r)
        Aout[((size_t)(b * SEQ + i0 + quad * 4 + r)) * DIM + (h0 + hh) * HD + dc * 16 + n] =
            (__bf16)oacc[hh][dc][r];
}

// ---------------------------------------------------------------------------
// K3: output projection. A(8192x768 bf16) @ Wp(fp32) + bp -> fp32 out.
// ---------------------------------------------------------------------------
__global__ __launch_bounds__(256) void gemm_proj(
    const unsigned short* __restrict__ A,
    const float* __restrict__ Wp,
    const float* __restrict__ bp,
    float* __restrict__ Out)
{
  __shared__ float As[64 * 20];
  __shared__ float Bs[16 * 68];

  const int t = threadIdx.x;
  const int tx = t & 15, ty = t >> 4;
  const int row0 = blockIdx.y * 64;
  const int col0 = blockIdx.x * 64;

  const int ar = t >> 2, ac = (t & 3) * 4;
  const int br = t >> 4, bc = (t & 15) * 4;

  float acc[4][4] = {};

  for (int k0 = 0; k0 < DIM; k0 += 16) {
    __syncthreads();
    {
      uint2 raw = *(const uint2*)(A + (size_t)(row0 + ar) * DIM + k0 + ac);
      float4 v = make_float4(bfraw2f(raw.x & 0xffffu), bfraw2f(raw.x >> 16),
                             bfraw2f(raw.y & 0xffffu), bfraw2f(raw.y >> 16));
      *(float4*)&As[ar * 20 + ac] = v;
    }
    *(float4*)&Bs[br * 68 + bc] = *(const float4*)(Wp + (size_t)(k0 + br) * DIM + col0 + bc);
    __syncthreads();
#pragma unroll
    for (int k = 0; k < 16; ++k) {
      float a0 = As[(ty * 4 + 0) * 20 + k];
      float a1 = As[(ty * 4 + 1) * 20 + k];
      float a2 = As[(ty * 4 + 2) * 20 + k];
      float a3 = As[(ty * 4 + 3) * 20 + k];
      float4 bv = *(const float4*)&Bs[k * 68 + tx * 4];
      acc[0][0] += a0 * bv.x; acc[0][1] += a0 * bv.y; acc[0][2] += a0 * bv.z; acc[0][3] += a0 * bv.w;
      acc[1][0] += a1 * bv.x; acc[1][1] += a1 * bv.y; acc[1][2] += a1 * bv.z; acc[1][3] += a1 * bv.w;
      acc[2][0] += a2 * bv.x; acc[2][1] += a2 * bv.y; acc[2][2] += a2 * bv.z; acc[2][3] += a2 * bv.w;
      acc[3][0] += a3 * bv.x; acc[3][1] += a3 * bv.y; acc[3][2] += a3 * bv.z; acc[3][3] += a3 * bv.w;
    }
  }

  const int col = col0 + tx * 4;
  float4 bb4 = *(const float4*)(bp + col);
#pragma unroll
  for (int u = 0; u < 4; ++u) {
    int row = row0 + ty * 4 + u;
    float4 o = make_float4(acc[u][0] + bb4.x, acc[u][1] + bb4.y,
                           acc[u][2] + bb4.z, acc[u][3] + bb4.w);
    *(float4*)&Out[(size_t)row * DIM + col] = o;
  }
}

extern "C" void kernel_launch(void* const* d_in, const int* in_sizes, int n_in,
                              void* d_out, int out_size, void* d_ws, size_t ws_size,
                              hipStream_t stream) {
  const float* x  = (const float*)d_in[0];
  const float* Wq = (const float*)d_in[1];
  const float* Wk = (const float*)d_in[2];
  const float* Wv = (const float*)d_in[3];
  const float* Wl = (const float*)d_in[4];
  const float* bl = (const float*)d_in[5];
  const float* Ww = (const float*)d_in[6];
  const float* bw = (const float*)d_in[7];
  const float* Wp = (const float*)d_in[8];
  const float* bp = (const float*)d_in[9];

  unsigned short* ws = (unsigned short*)d_ws;
  const size_t QSZ = (size_t)BATCH * NH * SEQ * HD;  // 6291456 elements
  __bf16*    Q  = (__bf16*)ws;
  __bf16*    K  = (__bf16*)(ws + QSZ);
  _Float16*  Vt = (_Float16*)(ws + 2 * QSZ);
  __bf16*    AO = (__bf16*)(ws + 3 * QSZ);

  gemm_qkv<<<dim3(DIM / 64, (BATCH * SEQ) / 64, 3), 256, 0, stream>>>(x, Wq, Wk, Wv, Q, K, Vt);
  attn_fused<<<dim3(SEQ / 16, BATCH), 256, 0, stream>>>(Q, K, Vt, Wl, bl, Ww, bw, AO);
  gemm_proj<<<dim3(DIM / 64, (BATCH * SEQ) / 64), 256, 0, stream>>>((const unsigned short*)AO, Wp, bp, (float*)d_out);
}

// Round 5
// 711.657 us; speedup vs baseline: 21.7753x; 2.7170x over previous
//
#include <hip/hip_runtime.h>
#include <hip/hip_bf16.h>

#define DIM 768
#define NH 12
#define HD 64
#define SEQ 1024
#define BATCH 8

typedef __bf16 bf16x8 __attribute__((ext_vector_type(8)));
typedef _Float16 f16x4 __attribute__((ext_vector_type(4)));
typedef float f32x4 __attribute__((ext_vector_type(4)));

// ---------------------------------------------------------------------------
// K0: transpose + cvt 768x768 fp32 W -> bf16 WT[n][k]. blockIdx.z selects.
// ---------------------------------------------------------------------------
__global__ __launch_bounds__(256) void wtrans(
    const float* __restrict__ Wq, const float* __restrict__ Wk,
    const float* __restrict__ Wv, const float* __restrict__ Wp,
    __bf16* __restrict__ Tq, __bf16* __restrict__ Tk,
    __bf16* __restrict__ Tv, __bf16* __restrict__ Tp)
{
  const int z = blockIdx.z;
  const float* W = (z==0) ? Wq : (z==1) ? Wk : (z==2) ? Wv : Wp;
  __bf16* T = (z==0) ? Tq : (z==1) ? Tk : (z==2) ? Tv : Tp;
  __shared__ float tile[32][33];
  const int t = threadIdx.x, tx = t & 31, ty = t >> 5;
  const int k0 = blockIdx.y * 32, n0 = blockIdx.x * 32;
#pragma unroll
  for (int u = 0; u < 4; ++u)
    tile[ty + u*8][tx] = W[(size_t)(k0 + ty + u*8) * DIM + n0 + tx];
  __syncthreads();
#pragma unroll
  for (int u = 0; u < 4; ++u)
    T[(size_t)(n0 + ty + u*8) * DIM + k0 + tx] = (__bf16)tile[tx][ty + u*8];
}

// ---------------------------------------------------------------------------
// K1: QKV projection, MFMA, LDS-free (frags straight from global/L2).
// 64x64 block tile, 4 waves in 2x2, each wave 2x2 of 16x16 MFMA tiles.
// z=0: Q*0.125 -> bf16 [b][h][i][d]; z=1: K -> bf16 [b][h][j][d];
// z=2: V -> f16 block-transposed Vt2[b][h][jb][d][jl] (jb=j>>4, jl=j&15).
// ---------------------------------------------------------------------------
__global__ __launch_bounds__(256) void gemm_qkv(
    const float* __restrict__ X,
    const __bf16* __restrict__ WqT, const __bf16* __restrict__ WkT,
    const __bf16* __restrict__ WvT,
    __bf16* __restrict__ Qo, __bf16* __restrict__ Ko, _Float16* __restrict__ Vt2)
{
  const int z = blockIdx.z;
  const __bf16* WT = (z==0) ? WqT : (z==1) ? WkT : WvT;
  const int t = threadIdx.x, lane = t & 63, w = t >> 6;
  const int n16 = lane & 15, q = lane >> 4;
  const int row_b = blockIdx.y * 64 + (w >> 1) * 32;
  const int col_b = blockIdx.x * 64 + (w & 1) * 32;

  f32x4 acc[2][2];
#pragma unroll
  for (int mt = 0; mt < 2; ++mt)
#pragma unroll
    for (int nt = 0; nt < 2; ++nt) acc[mt][nt] = (f32x4){0.f,0.f,0.f,0.f};

  for (int kb = 0; kb < DIM; kb += 32) {
    bf16x8 af[2], bg[2];
#pragma unroll
    for (int mt = 0; mt < 2; ++mt) {
      const float* xp = X + (size_t)(row_b + mt*16 + n16) * DIM + kb + q*8;
      float4 a0 = *(const float4*)xp;
      float4 a1 = *(const float4*)(xp + 4);
      bf16x8 v = { (__bf16)a0.x, (__bf16)a0.y, (__bf16)a0.z, (__bf16)a0.w,
                   (__bf16)a1.x, (__bf16)a1.y, (__bf16)a1.z, (__bf16)a1.w };
      af[mt] = v;
    }
#pragma unroll
    for (int nt = 0; nt < 2; ++nt)
      bg[nt] = *(const bf16x8*)(WT + (size_t)(col_b + nt*16 + n16) * DIM + kb + q*8);
#pragma unroll
    for (int mt = 0; mt < 2; ++mt)
#pragma unroll
      for (int nt = 0; nt < 2; ++nt)
        acc[mt][nt] = __builtin_amdgcn_mfma_f32_16x16x32_bf16(af[mt], bg[nt], acc[mt][nt], 0, 0, 0);
  }

  const float scale = (z == 0) ? 0.125f : 1.0f;
#pragma unroll
  for (int mt = 0; mt < 2; ++mt)
#pragma unroll
    for (int nt = 0; nt < 2; ++nt) {
      const int col = col_b + nt*16 + n16;
      const int h = col >> 6, d = col & 63;
#pragma unroll
      for (int r = 0; r < 4; ++r) {
        const int row = row_b + mt*16 + q*4 + r;
        const int bb = row >> 10, ii = row & 1023;
        const float v = acc[mt][nt][r] * scale;
        if (z == 2) {
          Vt2[((((size_t)bb*NH + h)*64 + (ii >> 4))*HD + d)*16 + (ii & 15)] = (_Float16)v;
        } else if (z == 1) {
          Ko[(((size_t)bb*NH + h)*SEQ + ii)*HD + d] = (__bf16)v;
        } else {
          Qo[(((size_t)bb*NH + h)*SEQ + ii)*HD + d] = (__bf16)v;
        }
      }
    }
}

// ---------------------------------------------------------------------------
// K2: fused talking-heads attention, all-MFMA.
// Block = (b, 16 q-rows), 4 waves; wave w: QK^T heads 3w..3w+2, premix/postmix
// for i-chunks 4w..4w+3, PV for g2 = 3w..3w+2.
// Chain: QK^T(bf16 mfma) -> Sl LDS -> premix(f16 mfma, A=Wl, C=bl) -> exp*linv
// -> postmix directly from regs (C-layout == B-layout) -> Pl LDS -> PV(f16).
// Fixed softmax max=0 (mixed scores O(1); no overflow in fp32).
// ---------------------------------------------------------------------------
__global__ __launch_bounds__(256) void attn_fused(
    const __bf16* __restrict__ Qg, const __bf16* __restrict__ Kg,
    const _Float16* __restrict__ Vt2,
    const float* __restrict__ Wl, const float* __restrict__ bl,
    const float* __restrict__ Ww, const float* __restrict__ bw,
    __bf16* __restrict__ Aout)
{
  __shared__ float Sl[2][12][324];     // [buf][h][i*20 + j]; strides tuned for banks
  __shared__ _Float16 Pl[16 * 248];    // [i*248 + g2*20 + j]

  const int t = threadIdx.x, lane = t & 63, w = t >> 6;
  const int n16 = lane & 15, q = lane >> 4;
  const int h0 = w * 3;
  const int b = blockIdx.y, i0 = blockIdx.x * 16;
  const size_t bbase = (size_t)b * NH * SEQ * HD;

  // constant fragments
  f16x4 wlA, wwA;
  f32x4 blC, bwC;
#pragma unroll
  for (int j = 0; j < 4; ++j) {
    const int k = q*4 + j;
    wlA[j] = (n16 < 12 && k < 12) ? (_Float16)Wl[n16*12 + k] : (_Float16)0.f;
    wwA[j] = (n16 < 12 && k < 12) ? (_Float16)Ww[n16*12 + k] : (_Float16)0.f;
    blC[j] = (k < 12) ? bl[k] : 0.f;
    bwC[j] = (k < 12) ? bw[k] : 0.f;
  }

  // Q B-frags for own 3 heads (reused all jt)
  bf16x8 qf[3][2];
#pragma unroll
  for (int hh = 0; hh < 3; ++hh)
#pragma unroll
    for (int cc = 0; cc < 2; ++cc)
      qf[hh][cc] = *(const bf16x8*)(Qg + bbase + ((size_t)(h0+hh)*SEQ + i0 + n16)*HD + cc*32 + q*8);

  const f32x4 z4 = {0.f, 0.f, 0.f, 0.f};

  // ---------------- Phase A: l[g][i] ----------------
  float lrun[4][4];
#pragma unroll
  for (int c = 0; c < 4; ++c)
#pragma unroll
    for (int r = 0; r < 4; ++r) lrun[c][r] = 0.f;

  for (int jt = 0; jt < SEQ/16; ++jt) {
    const int buf = jt & 1;
#pragma unroll
    for (int hh = 0; hh < 3; ++hh) {
      const __bf16* kp = Kg + bbase + ((size_t)(h0+hh)*SEQ + jt*16 + n16)*HD + q*8;
      bf16x8 k0 = *(const bf16x8*)kp;
      bf16x8 k1 = *(const bf16x8*)(kp + 32);
      f32x4 s = __builtin_amdgcn_mfma_f32_16x16x32_bf16(k0, qf[hh][0], z4, 0, 0, 0);
      s = __builtin_amdgcn_mfma_f32_16x16x32_bf16(k1, qf[hh][1], s, 0, 0, 0);
      *(f32x4*)&Sl[buf][h0+hh][n16*20 + q*4] = s;   // S[h][i=n16][j=4q..+3]
    }
    __syncthreads();
#pragma unroll
    for (int c = 0; c < 4; ++c) {
      const int i = w*4 + c;
      f16x4 sf;
#pragma unroll
      for (int dd = 0; dd < 4; ++dd) {
        int h = q*4 + dd; if (h > 11) h = 11;   // clamped (A-frag zero there)
        sf[dd] = (_Float16)Sl[buf][h][i*20 + n16];
      }
      f32x4 sm = __builtin_amdgcn_mfma_f32_16x16x16f16(wlA, sf, blC, 0, 0, 0);
#pragma unroll
      for (int r = 0; r < 4; ++r) lrun[c][r] += __expf(sm[r]);
    }
  }

  float linv[4][4];
#pragma unroll
  for (int c = 0; c < 4; ++c)
#pragma unroll
    for (int r = 0; r < 4; ++r) {
      float l = lrun[c][r];
      l += __shfl_xor(l, 1);
      l += __shfl_xor(l, 2);
      l += __shfl_xor(l, 4);
      l += __shfl_xor(l, 8);
      linv[c][r] = 1.0f / l;
    }

  // ---------------- Phase B: premix -> postmix -> PV ----------------
  f32x4 oacc[3][4];
#pragma unroll
  for (int hh = 0; hh < 3; ++hh)
#pragma unroll
    for (int dc = 0; dc < 4; ++dc) oacc[hh][dc] = z4;

  for (int jt = 0; jt < SEQ/16; ++jt) {
#pragma unroll
    for (int hh = 0; hh < 3; ++hh) {
      const __bf16* kp = Kg + bbase + ((size_t)(h0+hh)*SEQ + jt*16 + n16)*HD + q*8;
      bf16x8 k0 = *(const bf16x8*)kp;
      bf16x8 k1 = *(const bf16x8*)(kp + 32);
      f32x4 s = __builtin_amdgcn_mfma_f32_16x16x32_bf16(k0, qf[hh][0], z4, 0, 0, 0);
      s = __builtin_amdgcn_mfma_f32_16x16x32_bf16(k1, qf[hh][1], s, 0, 0, 0);
      *(f32x4*)&Sl[0][h0+hh][n16*20 + q*4] = s;
    }
    __syncthreads();
#pragma unroll
    for (int c = 0; c < 4; ++c) {
      const int i = w*4 + c;
      f16x4 sf;
#pragma unroll
      for (int dd = 0; dd < 4; ++dd) {
        int h = q*4 + dd; if (h > 11) h = 11;
        sf[dd] = (_Float16)Sl[0][h][i*20 + n16];
      }
      f32x4 sm = __builtin_amdgcn_mfma_f32_16x16x16f16(wlA, sf, blC, 0, 0, 0);
      f16x4 pnf;
#pragma unroll
      for (int r = 0; r < 4; ++r)
        pnf[r] = (_Float16)(__expf(sm[r]) * linv[c][r]);
      // C-layout of sm/pn == B-layout: feed postmix directly from registers
      f32x4 p2 = __builtin_amdgcn_mfma_f32_16x16x16f16(wwA, pnf, bwC, 0, 0, 0);
      if (q < 3) {
#pragma unroll
        for (int r = 0; r < 4; ++r)
          Pl[i*248 + (q*4 + r)*20 + n16] = (_Float16)p2[r];
      }
    }
    __syncthreads();
#pragma unroll
    for (int hh = 0; hh < 3; ++hh) {
      const int g2 = h0 + hh;
      f16x4 pa = *(const f16x4*)&Pl[n16*248 + g2*20 + q*4];  // A[i=n16][j=4q..+3]
      const _Float16* vb = Vt2 + (((size_t)(b*NH + g2)*64 + jt)*HD)*16;
#pragma unroll
      for (int dc = 0; dc < 4; ++dc) {
        f16x4 vf = *(const f16x4*)(vb + (size_t)(dc*16 + n16)*16 + q*4);
        oacc[hh][dc] = __builtin_amdgcn_mfma_f32_16x16x16f16(pa, vf, oacc[hh][dc], 0, 0, 0);
      }
    }
  }

  // epilogue: O[i=4q+r][d=dc*16+n16] per g2
#pragma unroll
  for (int hh = 0; hh < 3; ++hh)
#pragma unroll
    for (int dc = 0; dc < 4; ++dc)
#pragma unroll
      for (int r = 0; r < 4; ++r)
        Aout[((size_t)(b*SEQ + i0 + q*4 + r))*DIM + (h0+hh)*HD + dc*16 + n16] =
            (__bf16)oacc[hh][dc][r];
}

// ---------------------------------------------------------------------------
// K3: output projection, MFMA, LDS-free. AO bf16 @ WpT + bp -> fp32 out.
// ---------------------------------------------------------------------------
__global__ __launch_bounds__(256) void gemm_proj(
    const __bf16* __restrict__ A, const __bf16* __restrict__ WpT,
    const float* __restrict__ bp, float* __restrict__ Out)
{
  const int t = threadIdx.x, lane = t & 63, w = t >> 6;
  const int n16 = lane & 15, q = lane >> 4;
  const int row_b = blockIdx.y * 64 + (w >> 1) * 32;
  const int col_b = blockIdx.x * 64 + (w & 1) * 32;

  f32x4 acc[2][2];
#pragma unroll
  for (int nt = 0; nt < 2; ++nt) {
    const float bpv = bp[col_b + nt*16 + n16];
#pragma unroll
    for (int mt = 0; mt < 2; ++mt)
#pragma unroll
      for (int r = 0; r < 4; ++r) acc[mt][nt][r] = bpv;
  }

  for (int kb = 0; kb < DIM; kb += 32) {
    bf16x8 af[2], bg[2];
#pragma unroll
    for (int mt = 0; mt < 2; ++mt)
      af[mt] = *(const bf16x8*)(A + (size_t)(row_b + mt*16 + n16) * DIM + kb + q*8);
#pragma unroll
    for (int nt = 0; nt < 2; ++nt)
      bg[nt] = *(const bf16x8*)(WpT + (size_t)(col_b + nt*16 + n16) * DIM + kb + q*8);
#pragma unroll
    for (int mt = 0; mt < 2; ++mt)
#pragma unroll
      for (int nt = 0; nt < 2; ++nt)
        acc[mt][nt] = __builtin_amdgcn_mfma_f32_16x16x32_bf16(af[mt], bg[nt], acc[mt][nt], 0, 0, 0);
  }

#pragma unroll
  for (int mt = 0; mt < 2; ++mt)
#pragma unroll
    for (int nt = 0; nt < 2; ++nt)
#pragma unroll
      for (int r = 0; r < 4; ++r)
        Out[(size_t)(row_b + mt*16 + q*4 + r)*DIM + col_b + nt*16 + n16] = acc[mt][nt][r];
}

extern "C" void kernel_launch(void* const* d_in, const int* in_sizes, int n_in,
                              void* d_out, int out_size, void* d_ws, size_t ws_size,
                              hipStream_t stream) {
  const float* x  = (const float*)d_in[0];
  const float* Wq = (const float*)d_in[1];
  const float* Wk = (const float*)d_in[2];
  const float* Wv = (const float*)d_in[3];
  const float* Wl = (const float*)d_in[4];
  const float* bl = (const float*)d_in[5];
  const float* Ww = (const float*)d_in[6];
  const float* bw = (const float*)d_in[7];
  const float* Wp = (const float*)d_in[8];
  const float* bp = (const float*)d_in[9];

  char* p = (char*)d_ws;
  const size_t WSZ = (size_t)DIM * DIM * 2;                 // 1,179,648 B
  const size_t TSZ = (size_t)BATCH * NH * SEQ * HD * 2;     // 12,582,912 B
  __bf16*   WqT = (__bf16*)p;            p += WSZ;
  __bf16*   WkT = (__bf16*)p;            p += WSZ;
  __bf16*   WvT = (__bf16*)p;            p += WSZ;
  __bf16*   WpT = (__bf16*)p;            p += WSZ;
  __bf16*   Q   = (__bf16*)p;            p += TSZ;
  __bf16*   K   = (__bf16*)p;            p += TSZ;
  _Float16* V2  = (_Float16*)p;          p += TSZ;
  __bf16*   AO  = (__bf16*)p;            p += TSZ;

  wtrans<<<dim3(24, 24, 4), 256, 0, stream>>>(Wq, Wk, Wv, Wp, WqT, WkT, WvT, WpT);
  gemm_qkv<<<dim3(12, 128, 3), 256, 0, stream>>>(x, WqT, WkT, WvT, Q, K, V2);
  attn_fused<<<dim3(SEQ/16, BATCH), 256, 0, stream>>>(Q, K, V2, Wl, bl, Ww, bw, AO);
  gemm_proj<<<dim3(12, 128), 256, 0, stream>>>(AO, WpT, bp, (float*)d_out);
}

// Round 6
// 462.856 us; speedup vs baseline: 33.4803x; 1.5375x over previous
//
#include <hip/hip_runtime.h>
#include <hip/hip_bf16.h>

#define DIM 768
#define NH 12
#define HD 64
#define SEQ 1024
#define BATCH 8

typedef __bf16 bf16x8 __attribute__((ext_vector_type(8)));
typedef _Float16 f16x4 __attribute__((ext_vector_type(4)));
typedef float f32x4 __attribute__((ext_vector_type(4)));

// ---------------------------------------------------------------------------
// K-1: convert X fp32 -> bf16 (one-shot, ~38 MB traffic).
// ---------------------------------------------------------------------------
__global__ __launch_bounds__(256) void xcvt(
    const float* __restrict__ X, __bf16* __restrict__ Xb)
{
  const size_t i = ((size_t)blockIdx.x * 256 + threadIdx.x) * 8;
  float4 a0 = *(const float4*)(X + i);
  float4 a1 = *(const float4*)(X + i + 4);
  bf16x8 v = { (__bf16)a0.x, (__bf16)a0.y, (__bf16)a0.z, (__bf16)a0.w,
               (__bf16)a1.x, (__bf16)a1.y, (__bf16)a1.z, (__bf16)a1.w };
  *(bf16x8*)(Xb + i) = v;
}

// ---------------------------------------------------------------------------
// K0: transpose + cvt 768x768 fp32 W -> bf16 WT[n][k]. blockIdx.z selects.
// ---------------------------------------------------------------------------
__global__ __launch_bounds__(256) void wtrans(
    const float* __restrict__ Wq, const float* __restrict__ Wk,
    const float* __restrict__ Wv, const float* __restrict__ Wp,
    __bf16* __restrict__ Tq, __bf16* __restrict__ Tk,
    __bf16* __restrict__ Tv, __bf16* __restrict__ Tp)
{
  const int z = blockIdx.z;
  const float* W = (z==0) ? Wq : (z==1) ? Wk : (z==2) ? Wv : Wp;
  __bf16* T = (z==0) ? Tq : (z==1) ? Tk : (z==2) ? Tv : Tp;
  __shared__ float tile[32][33];
  const int t = threadIdx.x, tx = t & 31, ty = t >> 5;
  const int k0 = blockIdx.y * 32, n0 = blockIdx.x * 32;
#pragma unroll
  for (int u = 0; u < 4; ++u)
    tile[ty + u*8][tx] = W[(size_t)(k0 + ty + u*8) * DIM + n0 + tx];
  __syncthreads();
#pragma unroll
  for (int u = 0; u < 4; ++u)
    T[(size_t)(n0 + ty + u*8) * DIM + k0 + tx] = (__bf16)tile[tx][ty + u*8];
}

// ---------------------------------------------------------------------------
// K1: fused QKV projection, LDS-staged MFMA GEMM.
// C = Xb(8192x768) @ WT^T where WT = [WqT;WkT;WvT] (2304x768, k-contiguous).
// 128x128 block tile, 4 waves 2x2 (64x64/wave, 4x4 MFMA 16x16x32), BK=32.
// LDS rows padded to 40 elems (80 B): bank-stride 20 -> 2-way worst (free),
// 16B-aligned for ds_write_b128/ds_read_b128.
// Epilogue scatters per z: Q*0.125 bf16 [b][h][i][d]; K bf16 [b][h][j][d];
// V f16 block-transposed Vt2[b][h][jb][d][jl].
// ---------------------------------------------------------------------------
__global__ __launch_bounds__(256) void gemm_qkv(
    const __bf16* __restrict__ Xb, const __bf16* __restrict__ WT,
    __bf16* __restrict__ Qo, __bf16* __restrict__ Ko, _Float16* __restrict__ Vt2)
{
  __shared__ __bf16 As[128 * 40];
  __shared__ __bf16 Bs[128 * 40];

  const int t = threadIdx.x, lane = t & 63, w = t >> 6;
  const int n16 = lane & 15, q = lane >> 4;
  const int m0 = blockIdx.y * 128, n0 = blockIdx.x * 128;
  const int wm = (w >> 1) * 64, wn = (w & 1) * 64;

  const int srow = t >> 2, scol = (t & 3) * 8;   // staging: 64 rows/round
  const __bf16* Ag = Xb + (size_t)(m0 + srow) * DIM + scol;
  const __bf16* Bg = WT + (size_t)(n0 + srow) * DIM + scol;

  f32x4 acc[4][4];
#pragma unroll
  for (int mt = 0; mt < 4; ++mt)
#pragma unroll
    for (int nt = 0; nt < 4; ++nt) acc[mt][nt] = (f32x4){0.f,0.f,0.f,0.f};

  for (int kb = 0; kb < DIM; kb += 32) {
    __syncthreads();
    bf16x8 a0 = *(const bf16x8*)(Ag + kb);
    bf16x8 a1 = *(const bf16x8*)(Ag + (size_t)64 * DIM + kb);
    bf16x8 b0 = *(const bf16x8*)(Bg + kb);
    bf16x8 b1 = *(const bf16x8*)(Bg + (size_t)64 * DIM + kb);
    *(bf16x8*)&As[srow * 40 + scol] = a0;
    *(bf16x8*)&As[(srow + 64) * 40 + scol] = a1;
    *(bf16x8*)&Bs[srow * 40 + scol] = b0;
    *(bf16x8*)&Bs[(srow + 64) * 40 + scol] = b1;
    __syncthreads();

    bf16x8 af[4], bg[4];
#pragma unroll
    for (int mt = 0; mt < 4; ++mt)
      af[mt] = *(const bf16x8*)&As[(wm + mt*16 + n16) * 40 + q*8];
#pragma unroll
    for (int nt = 0; nt < 4; ++nt)
      bg[nt] = *(const bf16x8*)&Bs[(wn + nt*16 + n16) * 40 + q*8];
#pragma unroll
    for (int mt = 0; mt < 4; ++mt)
#pragma unroll
      for (int nt = 0; nt < 4; ++nt)
        acc[mt][nt] = __builtin_amdgcn_mfma_f32_16x16x32_bf16(af[mt], bg[nt], acc[mt][nt], 0, 0, 0);
  }

  // epilogue: z is uniform per block (n0 multiple of 128, 768 % 128 == 0)
#pragma unroll
  for (int nt = 0; nt < 4; ++nt) {
    const int n = n0 + wn + nt*16 + n16;
    const int z = n / DIM, c = n % DIM;
    const int h = c >> 6, d = c & 63;
#pragma unroll
    for (int mt = 0; mt < 4; ++mt) {
#pragma unroll
      for (int r = 0; r < 4; ++r) {
        const int row = m0 + wm + mt*16 + q*4 + r;
        const int bb = row >> 10, ii = row & 1023;
        const float v = acc[mt][nt][r];
        if (z == 0)
          Qo[(((size_t)bb*NH + h)*SEQ + ii)*HD + d] = (__bf16)(v * 0.125f);
        else if (z == 1)
          Ko[(((size_t)bb*NH + h)*SEQ + ii)*HD + d] = (__bf16)v;
        else
          Vt2[((((size_t)bb*NH + h)*64 + (ii >> 4))*HD + d)*16 + (ii & 15)] = (_Float16)v;
      }
    }
  }
}

// ---------------------------------------------------------------------------
// K2: fused talking-heads attention, all-MFMA (unchanged from round 5).
// ---------------------------------------------------------------------------
__global__ __launch_bounds__(256) void attn_fused(
    const __bf16* __restrict__ Qg, const __bf16* __restrict__ Kg,
    const _Float16* __restrict__ Vt2,
    const float* __restrict__ Wl, const float* __restrict__ bl,
    const float* __restrict__ Ww, const float* __restrict__ bw,
    __bf16* __restrict__ Aout)
{
  __shared__ float Sl[2][12][324];     // [buf][h][i*20 + j]
  __shared__ _Float16 Pl[16 * 248];    // [i*248 + g2*20 + j]

  const int t = threadIdx.x, lane = t & 63, w = t >> 6;
  const int n16 = lane & 15, q = lane >> 4;
  const int h0 = w * 3;
  const int b = blockIdx.y, i0 = blockIdx.x * 16;
  const size_t bbase = (size_t)b * NH * SEQ * HD;

  f16x4 wlA, wwA;
  f32x4 blC, bwC;
#pragma unroll
  for (int j = 0; j < 4; ++j) {
    const int k = q*4 + j;
    wlA[j] = (n16 < 12 && k < 12) ? (_Float16)Wl[n16*12 + k] : (_Float16)0.f;
    wwA[j] = (n16 < 12 && k < 12) ? (_Float16)Ww[n16*12 + k] : (_Float16)0.f;
    blC[j] = (k < 12) ? bl[k] : 0.f;
    bwC[j] = (k < 12) ? bw[k] : 0.f;
  }

  bf16x8 qf[3][2];
#pragma unroll
  for (int hh = 0; hh < 3; ++hh)
#pragma unroll
    for (int cc = 0; cc < 2; ++cc)
      qf[hh][cc] = *(const bf16x8*)(Qg + bbase + ((size_t)(h0+hh)*SEQ + i0 + n16)*HD + cc*32 + q*8);

  const f32x4 z4 = {0.f, 0.f, 0.f, 0.f};

  float lrun[4][4];
#pragma unroll
  for (int c = 0; c < 4; ++c)
#pragma unroll
    for (int r = 0; r < 4; ++r) lrun[c][r] = 0.f;

  for (int jt = 0; jt < SEQ/16; ++jt) {
    const int buf = jt & 1;
#pragma unroll
    for (int hh = 0; hh < 3; ++hh) {
      const __bf16* kp = Kg + bbase + ((size_t)(h0+hh)*SEQ + jt*16 + n16)*HD + q*8;
      bf16x8 k0 = *(const bf16x8*)kp;
      bf16x8 k1 = *(const bf16x8*)(kp + 32);
      f32x4 s = __builtin_amdgcn_mfma_f32_16x16x32_bf16(k0, qf[hh][0], z4, 0, 0, 0);
      s = __builtin_amdgcn_mfma_f32_16x16x32_bf16(k1, qf[hh][1], s, 0, 0, 0);
      *(f32x4*)&Sl[buf][h0+hh][n16*20 + q*4] = s;
    }
    __syncthreads();
#pragma unroll
    for (int c = 0; c < 4; ++c) {
      const int i = w*4 + c;
      f16x4 sf;
#pragma unroll
      for (int dd = 0; dd < 4; ++dd) {
        int h = q*4 + dd; if (h > 11) h = 11;
        sf[dd] = (_Float16)Sl[buf][h][i*20 + n16];
      }
      f32x4 sm = __builtin_amdgcn_mfma_f32_16x16x16f16(wlA, sf, blC, 0, 0, 0);
#pragma unroll
      for (int r = 0; r < 4; ++r) lrun[c][r] += __expf(sm[r]);
    }
  }

  float linv[4][4];
#pragma unroll
  for (int c = 0; c < 4; ++c)
#pragma unroll
    for (int r = 0; r < 4; ++r) {
      float l = lrun[c][r];
      l += __shfl_xor(l, 1);
      l += __shfl_xor(l, 2);
      l += __shfl_xor(l, 4);
      l += __shfl_xor(l, 8);
      linv[c][r] = 1.0f / l;
    }

  f32x4 oacc[3][4];
#pragma unroll
  for (int hh = 0; hh < 3; ++hh)
#pragma unroll
    for (int dc = 0; dc < 4; ++dc) oacc[hh][dc] = z4;

  for (int jt = 0; jt < SEQ/16; ++jt) {
#pragma unroll
    for (int hh = 0; hh < 3; ++hh) {
      const __bf16* kp = Kg + bbase + ((size_t)(h0+hh)*SEQ + jt*16 + n16)*HD + q*8;
      bf16x8 k0 = *(const bf16x8*)kp;
      bf16x8 k1 = *(const bf16x8*)(kp + 32);
      f32x4 s = __builtin_amdgcn_mfma_f32_16x16x32_bf16(k0, qf[hh][0], z4, 0, 0, 0);
      s = __builtin_amdgcn_mfma_f32_16x16x32_bf16(k1, qf[hh][1], s, 0, 0, 0);
      *(f32x4*)&Sl[0][h0+hh][n16*20 + q*4] = s;
    }
    __syncthreads();
#pragma unroll
    for (int c = 0; c < 4; ++c) {
      const int i = w*4 + c;
      f16x4 sf;
#pragma unroll
      for (int dd = 0; dd < 4; ++dd) {
        int h = q*4 + dd; if (h > 11) h = 11;
        sf[dd] = (_Float16)Sl[0][h][i*20 + n16];
      }
      f32x4 sm = __builtin_amdgcn_mfma_f32_16x16x16f16(wlA, sf, blC, 0, 0, 0);
      f16x4 pnf;
#pragma unroll
      for (int r = 0; r < 4; ++r)
        pnf[r] = (_Float16)(__expf(sm[r]) * linv[c][r]);
      f32x4 p2 = __builtin_amdgcn_mfma_f32_16x16x16f16(wwA, pnf, bwC, 0, 0, 0);
      if (q < 3) {
#pragma unroll
        for (int r = 0; r < 4; ++r)
          Pl[i*248 + (q*4 + r)*20 + n16] = (_Float16)p2[r];
      }
    }
    __syncthreads();
#pragma unroll
    for (int hh = 0; hh < 3; ++hh) {
      const int g2 = h0 + hh;
      f16x4 pa = *(const f16x4*)&Pl[n16*248 + g2*20 + q*4];
      const _Float16* vb = Vt2 + (((size_t)(b*NH + g2)*64 + jt)*HD)*16;
#pragma unroll
      for (int dc = 0; dc < 4; ++dc) {
        f16x4 vf = *(const f16x4*)(vb + (size_t)(dc*16 + n16)*16 + q*4);
        oacc[hh][dc] = __builtin_amdgcn_mfma_f32_16x16x16f16(pa, vf, oacc[hh][dc], 0, 0, 0);
      }
    }
  }

#pragma unroll
  for (int hh = 0; hh < 3; ++hh)
#pragma unroll
    for (int dc = 0; dc < 4; ++dc)
#pragma unroll
      for (int r = 0; r < 4; ++r)
        Aout[((size_t)(b*SEQ + i0 + q*4 + r))*DIM + (h0+hh)*HD + dc*16 + n16] =
            (__bf16)oacc[hh][dc][r];
}

// ---------------------------------------------------------------------------
// K3: output projection, LDS-staged MFMA GEMM. AO bf16 @ WpT + bp -> fp32.
// Same structure as K1 (128x128, BK=32, padded-40 LDS).
// ---------------------------------------------------------------------------
__global__ __launch_bounds__(256) void gemm_proj(
    const __bf16* __restrict__ A, const __bf16* __restrict__ WpT,
    const float* __restrict__ bp, float* __restrict__ Out)
{
  __shared__ __bf16 As[128 * 40];
  __shared__ __bf16 Bs[128 * 40];

  const int t = threadIdx.x, lane = t & 63, w = t >> 6;
  const int n16 = lane & 15, q = lane >> 4;
  const int m0 = blockIdx.y * 128, n0 = blockIdx.x * 128;
  const int wm = (w >> 1) * 64, wn = (w & 1) * 64;

  const int srow = t >> 2, scol = (t & 3) * 8;
  const __bf16* Ag = A + (size_t)(m0 + srow) * DIM + scol;
  const __bf16* Bg = WpT + (size_t)(n0 + srow) * DIM + scol;

  f32x4 acc[4][4];
#pragma unroll
  for (int nt = 0; nt < 4; ++nt) {
    const float bpv = bp[n0 + wn + nt*16 + n16];
#pragma unroll
    for (int mt = 0; mt < 4; ++mt)
#pragma unroll
      for (int r = 0; r < 4; ++r) acc[mt][nt][r] = bpv;
  }

  for (int kb = 0; kb < DIM; kb += 32) {
    __syncthreads();
    bf16x8 a0 = *(const bf16x8*)(Ag + kb);
    bf16x8 a1 = *(const bf16x8*)(Ag + (size_t)64 * DIM + kb);
    bf16x8 b0 = *(const bf16x8*)(Bg + kb);
    bf16x8 b1 = *(const bf16x8*)(Bg + (size_t)64 * DIM + kb);
    *(bf16x8*)&As[srow * 40 + scol] = a0;
    *(bf16x8*)&As[(srow + 64) * 40 + scol] = a1;
    *(bf16x8*)&Bs[srow * 40 + scol] = b0;
    *(bf16x8*)&Bs[(srow + 64) * 40 + scol] = b1;
    __syncthreads();

    bf16x8 af[4], bg[4];
#pragma unroll
    for (int mt = 0; mt < 4; ++mt)
      af[mt] = *(const bf16x8*)&As[(wm + mt*16 + n16) * 40 + q*8];
#pragma unroll
    for (int nt = 0; nt < 4; ++nt)
      bg[nt] = *(const bf16x8*)&Bs[(wn + nt*16 + n16) * 40 + q*8];
#pragma unroll
    for (int mt = 0; mt < 4; ++mt)
#pragma unroll
      for (int nt = 0; nt < 4; ++nt)
        acc[mt][nt] = __builtin_amdgcn_mfma_f32_16x16x32_bf16(af[mt], bg[nt], acc[mt][nt], 0, 0, 0);
  }

#pragma unroll
  for (int nt = 0; nt < 4; ++nt) {
    const int n = n0 + wn + nt*16 + n16;
#pragma unroll
    for (int mt = 0; mt < 4; ++mt)
#pragma unroll
      for (int r = 0; r < 4; ++r) {
        const int row = m0 + wm + mt*16 + q*4 + r;
        Out[(size_t)row * DIM + n] = acc[mt][nt][r];
      }
  }
}

extern "C" void kernel_launch(void* const* d_in, const int* in_sizes, int n_in,
                              void* d_out, int out_size, void* d_ws, size_t ws_size,
                              hipStream_t stream) {
  const float* x  = (const float*)d_in[0];
  const float* Wq = (const float*)d_in[1];
  const float* Wk = (const float*)d_in[2];
  const float* Wv = (const float*)d_in[3];
  const float* Wl = (const float*)d_in[4];
  const float* bl = (const float*)d_in[5];
  const float* Ww = (const float*)d_in[6];
  const float* bw = (const float*)d_in[7];
  const float* Wp = (const float*)d_in[8];
  const float* bp = (const float*)d_in[9];

  char* p = (char*)d_ws;
  const size_t WSZ = (size_t)DIM * DIM * 2;                 // 1,179,648 B
  const size_t TSZ = (size_t)BATCH * NH * SEQ * HD * 2;     // 12,582,912 B
  __bf16*   WqT = (__bf16*)p;            p += WSZ;   // WqT|WkT|WvT contiguous:
  __bf16*   WkT = (__bf16*)p;            p += WSZ;   // = the 2304x768 B matrix
  __bf16*   WvT = (__bf16*)p;            p += WSZ;
  __bf16*   WpT = (__bf16*)p;            p += WSZ;
  __bf16*   Q   = (__bf16*)p;            p += TSZ;
  __bf16*   K   = (__bf16*)p;            p += TSZ;
  _Float16* V2  = (_Float16*)p;          p += TSZ;
  __bf16*   AO  = (__bf16*)p;            p += TSZ;
  __bf16*   Xb  = (__bf16*)p;            p += TSZ;

  xcvt<<<dim3((BATCH*SEQ*DIM)/(256*8)), 256, 0, stream>>>(x, Xb);
  wtrans<<<dim3(24, 24, 4), 256, 0, stream>>>(Wq, Wk, Wv, Wp, WqT, WkT, WvT, WpT);
  gemm_qkv<<<dim3(18, 64), 256, 0, stream>>>(Xb, WqT, Q, K, V2);
  attn_fused<<<dim3(SEQ/16, BATCH), 256, 0, stream>>>(Q, K, V2, Wl, bl, Ww, bw, AO);
  gemm_proj<<<dim3(6, 64), 256, 0, stream>>>(AO, WpT, bp, (float*)d_out);
}

// Round 7
// 434.333 us; speedup vs baseline: 35.6790x; 1.0657x over previous
//
#include <hip/hip_runtime.h>
#include <hip/hip_bf16.h>

#define DIM 768
#define NH 12
#define HD 64
#define SEQ 1024
#define BATCH 8

typedef __bf16 bf16x8 __attribute__((ext_vector_type(8)));
typedef _Float16 f16x4 __attribute__((ext_vector_type(4)));
typedef float f32x4 __attribute__((ext_vector_type(4)));

// ---------------------------------------------------------------------------
// K-1: convert X fp32 -> bf16 (one-shot, ~38 MB traffic).
// ---------------------------------------------------------------------------
__global__ __launch_bounds__(256) void xcvt(
    const float* __restrict__ X, __bf16* __restrict__ Xb)
{
  const size_t i = ((size_t)blockIdx.x * 256 + threadIdx.x) * 8;
  float4 a0 = *(const float4*)(X + i);
  float4 a1 = *(const float4*)(X + i + 4);
  bf16x8 v = { (__bf16)a0.x, (__bf16)a0.y, (__bf16)a0.z, (__bf16)a0.w,
               (__bf16)a1.x, (__bf16)a1.y, (__bf16)a1.z, (__bf16)a1.w };
  *(bf16x8*)(Xb + i) = v;
}

// ---------------------------------------------------------------------------
// K0: transpose + cvt 768x768 fp32 W -> bf16 WT[n][k]. blockIdx.z selects.
// ---------------------------------------------------------------------------
__global__ __launch_bounds__(256) void wtrans(
    const float* __restrict__ Wq, const float* __restrict__ Wk,
    const float* __restrict__ Wv, const float* __restrict__ Wp,
    __bf16* __restrict__ Tq, __bf16* __restrict__ Tk,
    __bf16* __restrict__ Tv, __bf16* __restrict__ Tp)
{
  const int z = blockIdx.z;
  const float* W = (z==0) ? Wq : (z==1) ? Wk : (z==2) ? Wv : Wp;
  __bf16* T = (z==0) ? Tq : (z==1) ? Tk : (z==2) ? Tv : Tp;
  __shared__ float tile[32][33];
  const int t = threadIdx.x, tx = t & 31, ty = t >> 5;
  const int k0 = blockIdx.y * 32, n0 = blockIdx.x * 32;
#pragma unroll
  for (int u = 0; u < 4; ++u)
    tile[ty + u*8][tx] = W[(size_t)(k0 + ty + u*8) * DIM + n0 + tx];
  __syncthreads();
#pragma unroll
  for (int u = 0; u < 4; ++u)
    T[(size_t)(n0 + ty + u*8) * DIM + k0 + tx] = (__bf16)tile[tx][ty + u*8];
}

// ---------------------------------------------------------------------------
// K1: fused QKV projection, LDS-staged MFMA GEMM (unchanged from round 6).
// ---------------------------------------------------------------------------
__global__ __launch_bounds__(256) void gemm_qkv(
    const __bf16* __restrict__ Xb, const __bf16* __restrict__ WT,
    __bf16* __restrict__ Qo, __bf16* __restrict__ Ko, _Float16* __restrict__ Vt2)
{
  __shared__ __bf16 As[128 * 40];
  __shared__ __bf16 Bs[128 * 40];

  const int t = threadIdx.x, lane = t & 63, w = t >> 6;
  const int n16 = lane & 15, q = lane >> 4;
  const int m0 = blockIdx.y * 128, n0 = blockIdx.x * 128;
  const int wm = (w >> 1) * 64, wn = (w & 1) * 64;

  const int srow = t >> 2, scol = (t & 3) * 8;
  const __bf16* Ag = Xb + (size_t)(m0 + srow) * DIM + scol;
  const __bf16* Bg = WT + (size_t)(n0 + srow) * DIM + scol;

  f32x4 acc[4][4];
#pragma unroll
  for (int mt = 0; mt < 4; ++mt)
#pragma unroll
    for (int nt = 0; nt < 4; ++nt) acc[mt][nt] = (f32x4){0.f,0.f,0.f,0.f};

  for (int kb = 0; kb < DIM; kb += 32) {
    __syncthreads();
    bf16x8 a0 = *(const bf16x8*)(Ag + kb);
    bf16x8 a1 = *(const bf16x8*)(Ag + (size_t)64 * DIM + kb);
    bf16x8 b0 = *(const bf16x8*)(Bg + kb);
    bf16x8 b1 = *(const bf16x8*)(Bg + (size_t)64 * DIM + kb);
    *(bf16x8*)&As[srow * 40 + scol] = a0;
    *(bf16x8*)&As[(srow + 64) * 40 + scol] = a1;
    *(bf16x8*)&Bs[srow * 40 + scol] = b0;
    *(bf16x8*)&Bs[(srow + 64) * 40 + scol] = b1;
    __syncthreads();

    bf16x8 af[4], bg[4];
#pragma unroll
    for (int mt = 0; mt < 4; ++mt)
      af[mt] = *(const bf16x8*)&As[(wm + mt*16 + n16) * 40 + q*8];
#pragma unroll
    for (int nt = 0; nt < 4; ++nt)
      bg[nt] = *(const bf16x8*)&Bs[(wn + nt*16 + n16) * 40 + q*8];
#pragma unroll
    for (int mt = 0; mt < 4; ++mt)
#pragma unroll
      for (int nt = 0; nt < 4; ++nt)
        acc[mt][nt] = __builtin_amdgcn_mfma_f32_16x16x32_bf16(af[mt], bg[nt], acc[mt][nt], 0, 0, 0);
  }

#pragma unroll
  for (int nt = 0; nt < 4; ++nt) {
    const int n = n0 + wn + nt*16 + n16;
    const int z = n / DIM, c = n % DIM;
    const int h = c >> 6, d = c & 63;
#pragma unroll
    for (int mt = 0; mt < 4; ++mt) {
#pragma unroll
      for (int r = 0; r < 4; ++r) {
        const int row = m0 + wm + mt*16 + q*4 + r;
        const int bb = row >> 10, ii = row & 1023;
        const float v = acc[mt][nt][r];
        if (z == 0)
          Qo[(((size_t)bb*NH + h)*SEQ + ii)*HD + d] = (__bf16)(v * 0.125f);
        else if (z == 1)
          Ko[(((size_t)bb*NH + h)*SEQ + ii)*HD + d] = (__bf16)v;
        else
          Vt2[((((size_t)bb*NH + h)*64 + (ii >> 4))*HD + d)*16 + (ii & 15)] = (_Float16)v;
      }
    }
  }
}

// ---------------------------------------------------------------------------
// K2: fused talking-heads attention, all-MFMA, software-pipelined.
// Register prefetch of K(jt+1)/V(jt) hides global latency across the barrier;
// phase B runs PV lagged by one jt so each jt needs only ONE barrier.
// ---------------------------------------------------------------------------
__global__ __launch_bounds__(256, 2) void attn_fused(
    const __bf16* __restrict__ Qg, const __bf16* __restrict__ Kg,
    const _Float16* __restrict__ Vt2,
    const float* __restrict__ Wl, const float* __restrict__ bl,
    const float* __restrict__ Ww, const float* __restrict__ bw,
    __bf16* __restrict__ Aout)
{
  __shared__ float Sl[2][12][324];       // [buf][h][i*20 + j]
  __shared__ _Float16 Pl[2][16 * 248];   // [buf][i*248 + g2*20 + j]

  const int t = threadIdx.x, lane = t & 63, w = t >> 6;
  const int n16 = lane & 15, q = lane >> 4;
  const int h0 = w * 3;
  const int b = blockIdx.y, i0 = blockIdx.x * 16;
  const size_t bbase = (size_t)b * NH * SEQ * HD;

  f16x4 wlA, wwA;
  f32x4 blC, bwC;
#pragma unroll
  for (int j = 0; j < 4; ++j) {
    const int k = q*4 + j;
    wlA[j] = (n16 < 12 && k < 12) ? (_Float16)Wl[n16*12 + k] : (_Float16)0.f;
    wwA[j] = (n16 < 12 && k < 12) ? (_Float16)Ww[n16*12 + k] : (_Float16)0.f;
    blC[j] = (k < 12) ? bl[k] : 0.f;
    bwC[j] = (k < 12) ? bw[k] : 0.f;
  }

  bf16x8 qf[3][2];
#pragma unroll
  for (int hh = 0; hh < 3; ++hh)
#pragma unroll
    for (int cc = 0; cc < 2; ++cc)
      qf[hh][cc] = *(const bf16x8*)(Qg + bbase + ((size_t)(h0+hh)*SEQ + i0 + n16)*HD + cc*32 + q*8);

  const f32x4 z4 = {0.f, 0.f, 0.f, 0.f};

  // ---------------- Phase A: l[g][i], K prefetched one jt ahead ----------
  float lrun[4][4];
#pragma unroll
  for (int c = 0; c < 4; ++c)
#pragma unroll
    for (int r = 0; r < 4; ++r) lrun[c][r] = 0.f;

  bf16x8 kC[3][2], kN[3][2];
#pragma unroll
  for (int hh = 0; hh < 3; ++hh) {
    const __bf16* kp = Kg + bbase + ((size_t)(h0+hh)*SEQ + n16)*HD + q*8;
    kC[hh][0] = *(const bf16x8*)kp;
    kC[hh][1] = *(const bf16x8*)(kp + 32);
  }

#pragma unroll 2
  for (int jt = 0; jt < SEQ/16; ++jt) {
    const int buf = jt & 1;
    const int jn = (jt < SEQ/16 - 1) ? jt + 1 : jt;
#pragma unroll
    for (int hh = 0; hh < 3; ++hh) {
      const __bf16* kp = Kg + bbase + ((size_t)(h0+hh)*SEQ + jn*16 + n16)*HD + q*8;
      kN[hh][0] = *(const bf16x8*)kp;
      kN[hh][1] = *(const bf16x8*)(kp + 32);
    }
#pragma unroll
    for (int hh = 0; hh < 3; ++hh) {
      f32x4 s = __builtin_amdgcn_mfma_f32_16x16x32_bf16(kC[hh][0], qf[hh][0], z4, 0, 0, 0);
      s = __builtin_amdgcn_mfma_f32_16x16x32_bf16(kC[hh][1], qf[hh][1], s, 0, 0, 0);
      *(f32x4*)&Sl[buf][h0+hh][n16*20 + q*4] = s;
    }
    __syncthreads();
#pragma unroll
    for (int c = 0; c < 4; ++c) {
      const int i = w*4 + c;
      f16x4 sf;
#pragma unroll
      for (int dd = 0; dd < 4; ++dd) {
        int h = q*4 + dd; if (h > 11) h = 11;
        sf[dd] = (_Float16)Sl[buf][h][i*20 + n16];
      }
      f32x4 sm = __builtin_amdgcn_mfma_f32_16x16x16f16(wlA, sf, blC, 0, 0, 0);
#pragma unroll
      for (int r = 0; r < 4; ++r) lrun[c][r] += __expf(sm[r]);
    }
#pragma unroll
    for (int hh = 0; hh < 3; ++hh) { kC[hh][0] = kN[hh][0]; kC[hh][1] = kN[hh][1]; }
  }

  float linv[4][4];
#pragma unroll
  for (int c = 0; c < 4; ++c)
#pragma unroll
    for (int r = 0; r < 4; ++r) {
      float l = lrun[c][r];
      l += __shfl_xor(l, 1);
      l += __shfl_xor(l, 2);
      l += __shfl_xor(l, 4);
      l += __shfl_xor(l, 8);
      linv[c][r] = 1.0f / l;
    }

  // ---------------- Phase B: 1 barrier/jt, PV lagged by one ----------------
  f32x4 oacc[3][4];
#pragma unroll
  for (int hh = 0; hh < 3; ++hh)
#pragma unroll
    for (int dc = 0; dc < 4; ++dc) oacc[hh][dc] = z4;

  f16x4 vC[3][4], vN[3][4];
#pragma unroll
  for (int hh = 0; hh < 3; ++hh) {
    const __bf16* kp = Kg + bbase + ((size_t)(h0+hh)*SEQ + n16)*HD + q*8;
    kC[hh][0] = *(const bf16x8*)kp;
    kC[hh][1] = *(const bf16x8*)(kp + 32);
  }

#pragma unroll 2
  for (int jt = 0; jt < SEQ/16; ++jt) {
    const int buf = jt & 1;
    const int jn = (jt < SEQ/16 - 1) ? jt + 1 : jt;
    // prefetch K(jt+1)
#pragma unroll
    for (int hh = 0; hh < 3; ++hh) {
      const __bf16* kp = Kg + bbase + ((size_t)(h0+hh)*SEQ + jn*16 + n16)*HD + q*8;
      kN[hh][0] = *(const bf16x8*)kp;
      kN[hh][1] = *(const bf16x8*)(kp + 32);
    }
    // prefetch V(jt) (consumed by PV next interval)
#pragma unroll
    for (int hh = 0; hh < 3; ++hh) {
      const _Float16* vb = Vt2 + (((size_t)(b*NH + h0 + hh)*64 + jt)*HD)*16;
#pragma unroll
      for (int dc = 0; dc < 4; ++dc)
        vN[hh][dc] = *(const f16x4*)(vb + (size_t)(dc*16 + n16)*16 + q*4);
    }
    // S(jt)
#pragma unroll
    for (int hh = 0; hh < 3; ++hh) {
      f32x4 s = __builtin_amdgcn_mfma_f32_16x16x32_bf16(kC[hh][0], qf[hh][0], z4, 0, 0, 0);
      s = __builtin_amdgcn_mfma_f32_16x16x32_bf16(kC[hh][1], qf[hh][1], s, 0, 0, 0);
      *(f32x4*)&Sl[buf][h0+hh][n16*20 + q*4] = s;
    }
    __syncthreads();
    // premix -> exp -> postmix -> Pl[buf]
#pragma unroll
    for (int c = 0; c < 4; ++c) {
      const int i = w*4 + c;
      f16x4 sf;
#pragma unroll
      for (int dd = 0; dd < 4; ++dd) {
        int h = q*4 + dd; if (h > 11) h = 11;
        sf[dd] = (_Float16)Sl[buf][h][i*20 + n16];
      }
      f32x4 sm = __builtin_amdgcn_mfma_f32_16x16x16f16(wlA, sf, blC, 0, 0, 0);
      f16x4 pnf;
#pragma unroll
      for (int r = 0; r < 4; ++r)
        pnf[r] = (_Float16)(__expf(sm[r]) * linv[c][r]);
      f32x4 p2 = __builtin_amdgcn_mfma_f32_16x16x16f16(wwA, pnf, bwC, 0, 0, 0);
      if (q < 3) {
#pragma unroll
        for (int r = 0; r < 4; ++r)
          Pl[buf][i*248 + (q*4 + r)*20 + n16] = (_Float16)p2[r];
      }
    }
    // PV(jt-1) from the other buffer, V frags prefetched last interval
    if (jt > 0) {
#pragma unroll
      for (int hh = 0; hh < 3; ++hh) {
        const int g2 = h0 + hh;
        f16x4 pa = *(const f16x4*)&Pl[1 - buf][n16*248 + g2*20 + q*4];
#pragma unroll
        for (int dc = 0; dc < 4; ++dc)
          oacc[hh][dc] = __builtin_amdgcn_mfma_f32_16x16x16f16(pa, vC[hh][dc], oacc[hh][dc], 0, 0, 0);
      }
    }
    // rotate prefetch buffers
#pragma unroll
    for (int hh = 0; hh < 3; ++hh) {
      kC[hh][0] = kN[hh][0]; kC[hh][1] = kN[hh][1];
#pragma unroll
      for (int dc = 0; dc < 4; ++dc) vC[hh][dc] = vN[hh][dc];
    }
  }
  __syncthreads();
  // tail: PV(63) from Pl[1], vC = V(63)
#pragma unroll
  for (int hh = 0; hh < 3; ++hh) {
    const int g2 = h0 + hh;
    f16x4 pa = *(const f16x4*)&Pl[1][n16*248 + g2*20 + q*4];
#pragma unroll
    for (int dc = 0; dc < 4; ++dc)
      oacc[hh][dc] = __builtin_amdgcn_mfma_f32_16x16x16f16(pa, vC[hh][dc], oacc[hh][dc], 0, 0, 0);
  }

#pragma unroll
  for (int hh = 0; hh < 3; ++hh)
#pragma unroll
    for (int dc = 0; dc < 4; ++dc)
#pragma unroll
      for (int r = 0; r < 4; ++r)
        Aout[((size_t)(b*SEQ + i0 + q*4 + r))*DIM + (h0+hh)*HD + dc*16 + n16] =
            (__bf16)oacc[hh][dc][r];
}

// ---------------------------------------------------------------------------
// K3: output projection, LDS-staged MFMA GEMM (unchanged from round 6).
// ---------------------------------------------------------------------------
__global__ __launch_bounds__(256) void gemm_proj(
    const __bf16* __restrict__ A, const __bf16* __restrict__ WpT,
    const float* __restrict__ bp, float* __restrict__ Out)
{
  __shared__ __bf16 As[128 * 40];
  __shared__ __bf16 Bs[128 * 40];

  const int t = threadIdx.x, lane = t & 63, w = t >> 6;
  const int n16 = lane & 15, q = lane >> 4;
  const int m0 = blockIdx.y * 128, n0 = blockIdx.x * 128;
  const int wm = (w >> 1) * 64, wn = (w & 1) * 64;

  const int srow = t >> 2, scol = (t & 3) * 8;
  const __bf16* Ag = A + (size_t)(m0 + srow) * DIM + scol;
  const __bf16* Bg = WpT + (size_t)(n0 + srow) * DIM + scol;

  f32x4 acc[4][4];
#pragma unroll
  for (int nt = 0; nt < 4; ++nt) {
    const float bpv = bp[n0 + wn + nt*16 + n16];
#pragma unroll
    for (int mt = 0; mt < 4; ++mt)
#pragma unroll
      for (int r = 0; r < 4; ++r) acc[mt][nt][r] = bpv;
  }

  for (int kb = 0; kb < DIM; kb += 32) {
    __syncthreads();
    bf16x8 a0 = *(const bf16x8*)(Ag + kb);
    bf16x8 a1 = *(const bf16x8*)(Ag + (size_t)64 * DIM + kb);
    bf16x8 b0 = *(const bf16x8*)(Bg + kb);
    bf16x8 b1 = *(const bf16x8*)(Bg + (size_t)64 * DIM + kb);
    *(bf16x8*)&As[srow * 40 + scol] = a0;
    *(bf16x8*)&As[(srow + 64) * 40 + scol] = a1;
    *(bf16x8*)&Bs[srow * 40 + scol] = b0;
    *(bf16x8*)&Bs[(srow + 64) * 40 + scol] = b1;
    __syncthreads();

    bf16x8 af[4], bg[4];
#pragma unroll
    for (int mt = 0; mt < 4; ++mt)
      af[mt] = *(const bf16x8*)&As[(wm + mt*16 + n16) * 40 + q*8];
#pragma unroll
    for (int nt = 0; nt < 4; ++nt)
      bg[nt] = *(const bf16x8*)&Bs[(wn + nt*16 + n16) * 40 + q*8];
#pragma unroll
    for (int mt = 0; mt < 4; ++mt)
#pragma unroll
      for (int nt = 0; nt < 4; ++nt)
        acc[mt][nt] = __builtin_amdgcn_mfma_f32_16x16x32_bf16(af[mt], bg[nt], acc[mt][nt], 0, 0, 0);
  }

#pragma unroll
  for (int nt = 0; nt < 4; ++nt) {
    const int n = n0 + wn + nt*16 + n16;
#pragma unroll
    for (int mt = 0; mt < 4; ++mt)
#pragma unroll
      for (int r = 0; r < 4; ++r) {
        const int row = m0 + wm + mt*16 + q*4 + r;
        Out[(size_t)row * DIM + n] = acc[mt][nt][r];
      }
  }
}

extern "C" void kernel_launch(void* const* d_in, const int* in_sizes, int n_in,
                              void* d_out, int out_size, void* d_ws, size_t ws_size,
                              hipStream_t stream) {
  const float* x  = (const float*)d_in[0];
  const float* Wq = (const float*)d_in[1];
  const float* Wk = (const float*)d_in[2];
  const float* Wv = (const float*)d_in[3];
  const float* Wl = (const float*)d_in[4];
  const float* bl = (const float*)d_in[5];
  const float* Ww = (const float*)d_in[6];
  const float* bw = (const float*)d_in[7];
  const float* Wp = (const float*)d_in[8];
  const float* bp = (const float*)d_in[9];

  char* p = (char*)d_ws;
  const size_t WSZ = (size_t)DIM * DIM * 2;                 // 1,179,648 B
  const size_t TSZ = (size_t)BATCH * NH * SEQ * HD * 2;     // 12,582,912 B
  __bf16*   WqT = (__bf16*)p;            p += WSZ;   // WqT|WkT|WvT contiguous:
  __bf16*   WkT = (__bf16*)p;            p += WSZ;   // = the 2304x768 B matrix
  __bf16*   WvT = (__bf16*)p;            p += WSZ;
  __bf16*   WpT = (__bf16*)p;            p += WSZ;
  __bf16*   Q   = (__bf16*)p;            p += TSZ;
  __bf16*   K   = (__bf16*)p;            p += TSZ;
  _Float16* V2  = (_Float16*)p;          p += TSZ;
  __bf16*   AO  = (__bf16*)p;            p += TSZ;
  __bf16*   Xb  = (__bf16*)p;            p += TSZ;

  xcvt<<<dim3((BATCH*SEQ*DIM)/(256*8)), 256, 0, stream>>>(x, Xb);
  wtrans<<<dim3(24, 24, 4), 256, 0, stream>>>(Wq, Wk, Wv, Wp, WqT, WkT, WvT, WpT);
  gemm_qkv<<<dim3(18, 64), 256, 0, stream>>>(Xb, WqT, Q, K, V2);
  attn_fused<<<dim3(SEQ/16, BATCH), 256, 0, stream>>>(Q, K, V2, Wl, bl, Ww, bw, AO);
  gemm_proj<<<dim3(6, 64), 256, 0, stream>>>(AO, WpT, bp, (float*)d_out);
}